// Round 3
// baseline (140.693 us; speedup 1.0000x reference)
//
#include <hip/hip_runtime.h>

#define B_ 16
#define T_ 800
#define D_ 256
#define K_ 64
#define TSPLIT 8   // kernelB t-chunks of 100

// ---------------- Kernel A: dist -> softmax over K -> r[b][t][k], S[b][k] ----------------
// grid = 800 blocks x 256 thr (4 waves). block = (b, 16 t-rows); wave w owns t = t0+w*4+j,
// lane = k. mu d-chunk (64 f) lives in VGPRs (via swizzled LDS stage); x rows via
// wave-uniform pointer -> s_load. Inner loop: pure v_fmac(s_x, v_mu).
__global__ __launch_bounds__(256) void kernelA(
    const float* __restrict__ x, const float* __restrict__ mu,
    const float* __restrict__ prec, float* __restrict__ r, float* __restrict__ S)
{
    __shared__ float4 muL[64 * 16];   // swizzled: row k, f4 i at slot k*16 + ((i+k)&15)
    __shared__ float sblk[64];

    const int tid  = threadIdx.x;
    const int lane = tid & 63;
    const int w    = __builtin_amdgcn_readfirstlane(tid >> 6);   // 0..3
    const int b    = blockIdx.x / 50;
    const int t0   = (blockIdx.x % 50) * 16;

    if (tid < 64) sblk[tid] = 0.f;

    // xx[j] = ||x_t||^2 for this wave's 4 rows (lane-parallel + shuffle reduce)
    float xx[4];
    #pragma unroll
    for (int j = 0; j < 4; ++j) {
        const int t = t0 + w * 4 + j;
        float4 v = ((const float4*)(x + (size_t)(b * T_ + t) * D_))[lane];
        float s = v.x*v.x + v.y*v.y + v.z*v.z + v.w*v.w;
        #pragma unroll
        for (int off = 32; off > 0; off >>= 1) s += __shfl_xor(s, off);
        xx[j] = s;
    }
    const float pk = prec[lane];
    const float p2 = pk * pk;

    float acc[4] = {0.f, 0.f, 0.f, 0.f};
    float mm = 0.f;

    for (int c = 0; c < 4; ++c) {
        __syncthreads();
        // stage mu c-chunk (64 k x 64 d) into swizzled LDS; coalesced global reads
        #pragma unroll
        for (int jj = 0; jj < 4; ++jj) {
            int g = tid + jj * 256;            // global f4 idx: k = g>>4, i = g&15
            int k = g >> 4, i = g & 15;
            muL[k * 16 + ((i + k) & 15)] = ((const float4*)(mu + (size_t)k * D_ + c * 64))[i];
        }
        __syncthreads();
        // own row chunk -> 64 VGPRs (conflict-free: slot group (i+k)%8 spreads 8 lanes/group)
        float4 m[16];
        #pragma unroll
        for (int i = 0; i < 16; ++i) m[i] = muL[lane * 16 + ((i + lane) & 15)];
        #pragma unroll
        for (int i = 0; i < 16; ++i) {
            mm = fmaf(m[i].x, m[i].x, mm); mm = fmaf(m[i].y, m[i].y, mm);
            mm = fmaf(m[i].z, m[i].z, mm); mm = fmaf(m[i].w, m[i].w, mm);
        }
        // 4 t-rows: x chunk via wave-uniform pointer (scalar loads), 64 fmac each
        #pragma unroll
        for (int j = 0; j < 4; ++j) {
            const int t = t0 + w * 4 + j;
            const float* xt = x + (size_t)(b * T_ + t) * D_ + c * 64;
            float a = acc[j];
            #pragma unroll
            for (int i = 0; i < 16; ++i) {
                a = fmaf(xt[i * 4 + 0], m[i].x, a);
                a = fmaf(xt[i * 4 + 1], m[i].y, a);
                a = fmaf(xt[i * 4 + 2], m[i].z, a);
                a = fmaf(xt[i * 4 + 3], m[i].w, a);
            }
            acc[j] = a;
        }
    }

    // softmax over k (full wave) for each of the 4 rows; accumulate S
    float sacc = 0.f;
    #pragma unroll
    for (int j = 0; j < 4; ++j) {
        const int t = t0 + w * 4 + j;
        float llk = p2 * (2.f * acc[j] - xx[j] - mm);
        float mx = llk;
        #pragma unroll
        for (int off = 32; off > 0; off >>= 1) mx = fmaxf(mx, __shfl_xor(mx, off));
        float e = __expf(llk - mx);
        float sum = e;
        #pragma unroll
        for (int off = 32; off > 0; off >>= 1) sum += __shfl_xor(sum, off);
        float rv = e / sum;
        r[(size_t)(b * T_ + t) * K_ + lane] = rv;   // coalesced 256B per (w,t)
        sacc += rv;
    }
    atomicAdd(&sblk[lane], sacc);
    __syncthreads();
    if (tid < 64) atomicAdd(&S[b * K_ + tid], sblk[tid]);
}

// ---------------- Kernel B: Ppart[ts][b][k][d] = sum_{t in chunk} r[b][t][k] * x[b][t][d] --
// grid = 16b * 4dc * 8ts = 512 blocks x 256 thr (4 waves; wave w owns 25 t).
// lane = k, acc[64] = d-chunk in VGPRs. r: coalesced vload; x: wave-uniform -> s_load.
// Block reduces its 4 waves via LDS buf[d][k] (bank = k%32, 2-way = free), one write/block.
__global__ __launch_bounds__(256) void kernelB(
    const float* __restrict__ x, const float* __restrict__ r, float* __restrict__ Pp)
{
    __shared__ float buf[64 * 64];    // [d][k]

    const int tid  = threadIdx.x;
    const int lane = tid & 63;
    const int w    = __builtin_amdgcn_readfirstlane(tid >> 6);
    const int bid  = blockIdx.x;
    const int b    = bid >> 5;
    const int dc   = (bid >> 3) & 3;
    const int ts   = bid & 7;

    #pragma unroll
    for (int i = 0; i < 4; ++i)
        ((float4*)buf)[tid + i * 256] = make_float4(0.f, 0.f, 0.f, 0.f);

    float acc[64];
    #pragma unroll
    for (int i = 0; i < 64; ++i) acc[i] = 0.f;

    const int tbase = ts * 100 + w * 25;
    for (int tt = 0; tt < 25; ++tt) {
        const int t = tbase + tt;
        const float rv = r[(size_t)(b * T_ + t) * K_ + lane];           // coalesced
        const float* xt = x + (size_t)(b * T_ + t) * D_ + dc * 64;      // uniform -> s_load
        #pragma unroll
        for (int i = 0; i < 64; ++i) acc[i] = fmaf(xt[i], rv, acc[i]);
    }

    __syncthreads();
    #pragma unroll
    for (int i = 0; i < 64; ++i) atomicAdd(&buf[i * 64 + lane], acc[i]);  // 2-way banks, free
    __syncthreads();

    // write 64k x 64d slice: thread -> (k = tid>>2, d0 = (tid&3)*16)
    const int k = tid >> 2, d0 = (tid & 3) * 16;
    float* dst = Pp + ((size_t)(ts * B_ + b) * K_ + k) * D_ + dc * 64 + d0;
    #pragma unroll
    for (int i = 0; i < 16; i += 4) {
        float4 v;
        v.x = buf[(d0 + i + 0) * 64 + k];
        v.y = buf[(d0 + i + 1) * 64 + k];
        v.z = buf[(d0 + i + 2) * 64 + k];
        v.w = buf[(d0 + i + 3) * 64 + k];
        *(float4*)(dst + i) = v;
    }
}

// ---------------- Kernel C: out = (sum_s Ppart)*inv - (S*inv)*mu ----------------
// grid = B*K = 1024 blocks x 64 thr; lane = d-float4
__global__ __launch_bounds__(64) void kernelC(
    const float* __restrict__ Pp, const float* __restrict__ S,
    const float* __restrict__ mu, float* __restrict__ out)
{
    const int bk   = blockIdx.x;
    const int b    = bk >> 6, k = bk & 63;
    const int lane = threadIdx.x;

    float4 p = make_float4(0.f, 0.f, 0.f, 0.f);
    #pragma unroll
    for (int s = 0; s < TSPLIT; ++s) {
        float4 v = ((const float4*)(Pp + ((size_t)(s * B_ + b) * K_ + k) * D_))[lane];
        p.x += v.x; p.y += v.y; p.z += v.z; p.w += v.w;
    }
    const float sv  = S[bk];
    const float inv = 1.f / (sv + 1e-9f);
    const float sm  = sv * inv;
    float4 m = ((const float4*)(mu + (size_t)k * D_))[lane];
    float4 o;
    o.x = p.x * inv - sm * m.x;
    o.y = p.y * inv - sm * m.y;
    o.z = p.z * inv - sm * m.z;
    o.w = p.w * inv - sm * m.w;
    ((float4*)out)[(size_t)bk * 64 + lane] = o;
}

extern "C" void kernel_launch(void* const* d_in, const int* in_sizes, int n_in,
                              void* d_out, int out_size, void* d_ws, size_t ws_size,
                              hipStream_t stream) {
    const float* x    = (const float*)d_in[0];
    const float* mu   = (const float*)d_in[1];
    const float* prec = (const float*)d_in[2];
    float* out = (float*)d_out;

    float* r  = (float*)d_ws;                                 // B*T*K = 819200 f
    float* Pp = r + (size_t)B_ * T_ * K_;                     // 8*B*K*D = 2097152 f
    float* S  = Pp + (size_t)TSPLIT * B_ * K_ * D_;           // B*K = 1024 f

    hipMemsetAsync(S, 0, (size_t)B_ * K_ * sizeof(float), stream);

    kernelA<<<800, 256, 0, stream>>>(x, mu, prec, r, S);
    kernelB<<<16 * 4 * TSPLIT, 256, 0, stream>>>(x, r, Pp);
    kernelC<<<B_ * K_, 64, 0, stream>>>(Pp, S, mu, out);
}

// Round 4
// 97.846 us; speedup vs baseline: 1.4379x; 1.4379x over previous
//
#include <hip/hip_runtime.h>

#define B_ 16
#define T_ 800
#define D_ 256
#define K_ 64
#define NTILE 13     // ceil(800/64) t-tiles for kernel A
#define TSPLIT 4     // kernel B t-split

// ---------------- Kernel A: llk -> softmax over K -> r (k-swizzled), Spart ----------------
// grid = 16 * 13 = 208 blocks, 256 thr. Tile: 64 t x 64 k.
// thread = (tx=tid>>4, ky=tid&15): owns t = t0+tx*4+i (i<4), k = ky+16j (j<4).
// Strided k-assignment makes mus[] b128 reads hit all 8 bank-groups (2-way = free).
__global__ __launch_bounds__(256, 2) void kernelA(
    const float* __restrict__ x, const float* __restrict__ mu,
    const float* __restrict__ prec, float* __restrict__ r2, float* __restrict__ Spart)
{
    __shared__ float xs[64][68];    // x tile chunk [t][d], pad 68 (17 f4)
    __shared__ float mus[64][68];   // mu chunk [k][d]
    __shared__ float xxs[64];
    __shared__ float mms[64];
    __shared__ float sred[4][64];

    const int tid  = threadIdx.x;
    const int tx   = tid >> 4;     // 0..15
    const int ky   = tid & 15;
    const int b    = blockIdx.x / NTILE;
    const int tile = blockIdx.x % NTILE;
    const int t0   = tile * 64;

    float acc[4][4];               // [i=t][j=k]
    #pragma unroll
    for (int i = 0; i < 4; ++i)
        #pragma unroll
        for (int j = 0; j < 4; ++j) acc[i][j] = 0.f;

    // per-thread partial squares: thread covers quarter sq of row srow (accumulated over chunks)
    const int srow = tid >> 2, sq = tid & 3;
    float xxp = 0.f, mmp = 0.f;

    #pragma unroll 1
    for (int c = 0; c < 4; ++c) {
        __syncthreads();
        // stage 64x64 chunks of x and mu (coalesced: 16 lanes x 16B per row segment)
        #pragma unroll
        for (int q = 0; q < 4; ++q) {
            const int row  = q * 16 + tx;
            int trow = t0 + row; if (trow > T_ - 1) trow = T_ - 1;
            *(float4*)&xs[row][ky * 4] =
                *(const float4*)(x + (size_t)(b * T_ + trow) * D_ + c * 64 + ky * 4);
            *(float4*)&mus[row][ky * 4] =
                *(const float4*)(mu + (size_t)row * D_ + c * 64 + ky * 4);
        }
        __syncthreads();
        // xx / mm partial accumulation (cheap: 8 b128 + 64 FMA per thread per chunk)
        #pragma unroll
        for (int m = 0; m < 4; ++m) {
            float4 v = *(const float4*)&xs[srow][sq * 16 + m * 4];
            xxp = fmaf(v.x, v.x, xxp); xxp = fmaf(v.y, v.y, xxp);
            xxp = fmaf(v.z, v.z, xxp); xxp = fmaf(v.w, v.w, xxp);
            float4 u = *(const float4*)&mus[srow][sq * 16 + m * 4];
            mmp = fmaf(u.x, u.x, mmp); mmp = fmaf(u.y, u.y, mmp);
            mmp = fmaf(u.z, u.z, mmp); mmp = fmaf(u.w, u.w, mmp);
        }
        // main: 16 d-groups of 4; per group: 8 b128 reads, 64 FMA
        #pragma unroll 4
        for (int dg = 0; dg < 16; ++dg) {
            float4 xv[4], mv[4];
            #pragma unroll
            for (int i = 0; i < 4; ++i) xv[i] = *(const float4*)&xs[tx * 4 + i][dg * 4];
            #pragma unroll
            for (int j = 0; j < 4; ++j) mv[j] = *(const float4*)&mus[ky + 16 * j][dg * 4];
            #pragma unroll
            for (int i = 0; i < 4; ++i)
                #pragma unroll
                for (int j = 0; j < 4; ++j) {
                    float a = acc[i][j];
                    a = fmaf(xv[i].x, mv[j].x, a);
                    a = fmaf(xv[i].y, mv[j].y, a);
                    a = fmaf(xv[i].z, mv[j].z, a);
                    a = fmaf(xv[i].w, mv[j].w, a);
                    acc[i][j] = a;
                }
        }
    }

    // finalize xx / mm (reduce the 4 quarter-threads of each row)
    xxp += __shfl_xor(xxp, 1); xxp += __shfl_xor(xxp, 2);
    mmp += __shfl_xor(mmp, 1); mmp += __shfl_xor(mmp, 2);
    if (sq == 0) { xxs[srow] = xxp; mms[srow] = mmp; }
    __syncthreads();

    float p2[4], mmk[4];
    #pragma unroll
    for (int j = 0; j < 4; ++j) {
        float p = prec[ky + 16 * j];
        p2[j] = p * p;
        mmk[j] = mms[ky + 16 * j];
    }

    float sacc[4] = {0.f, 0.f, 0.f, 0.f};
    #pragma unroll
    for (int i = 0; i < 4; ++i) {
        const int tl = tx * 4 + i;
        const bool valid = (t0 + tl) < T_;
        const float xxv = xxs[tl];
        float llk[4];
        #pragma unroll
        for (int j = 0; j < 4; ++j)
            llk[j] = p2[j] * (2.f * acc[i][j] - xxv - mmk[j]);
        float mx = fmaxf(fmaxf(llk[0], llk[1]), fmaxf(llk[2], llk[3]));
        mx = fmaxf(mx, __shfl_xor(mx, 1)); mx = fmaxf(mx, __shfl_xor(mx, 2));
        mx = fmaxf(mx, __shfl_xor(mx, 4)); mx = fmaxf(mx, __shfl_xor(mx, 8));
        float e[4], ps = 0.f;
        #pragma unroll
        for (int j = 0; j < 4; ++j) { e[j] = __expf(llk[j] - mx); ps += e[j]; }
        ps += __shfl_xor(ps, 1); ps += __shfl_xor(ps, 2);
        ps += __shfl_xor(ps, 4); ps += __shfl_xor(ps, 8);
        const float inv = 1.f / ps;
        float4 rv;
        rv.x = e[0] * inv; rv.y = e[1] * inv; rv.z = e[2] * inv; rv.w = e[3] * inv;
        if (valid) {
            // k-swizzled store: slot ky*4+j holds k = ky+16j; f4-coalesced
            *(float4*)(r2 + (size_t)(b * T_ + t0 + tl) * K_ + ky * 4) = rv;
            sacc[0] += rv.x; sacc[1] += rv.y; sacc[2] += rv.z; sacc[3] += rv.w;
        }
    }
    // reduce S over the wave's 4 tx-groups, then cross-wave via LDS
    #pragma unroll
    for (int j = 0; j < 4; ++j) {
        sacc[j] += __shfl_xor(sacc[j], 16);
        sacc[j] += __shfl_xor(sacc[j], 32);
    }
    const int w = tid >> 6;
    if ((tid & 48) == 0) {
        #pragma unroll
        for (int j = 0; j < 4; ++j) sred[w][ky * 4 + j] = sacc[j];
    }
    __syncthreads();
    if (tid < 64) {
        const int k = tid;
        const int slot = (k & 15) * 4 + (k >> 4);
        float s = sred[0][slot] + sred[1][slot] + sred[2][slot] + sred[3][slot];
        Spart[((size_t)b * NTILE + tile) * K_ + k] = s;
    }
}

// ---------------- Kernel B: Pp[ts][b][k][d] = sum_t r[t,k] * x[t,d] ----------------
// grid = 16b * 4dc * 4ts = 256 blocks (1/CU), 256 thr.
// thread = (kx=tid>>4, dy=tid&15): k = kx+16j (matches A's swizzle: rs f4 slot kx = those 4 k).
__global__ __launch_bounds__(256, 2) void kernelB(
    const float* __restrict__ x, const float* __restrict__ r2, float* __restrict__ Pp)
{
    __shared__ float xs[25][68];
    __shared__ float rs[25][68];

    const int tid = threadIdx.x;
    const int kx  = tid >> 4;
    const int dy  = tid & 15;
    const int bid = blockIdx.x;
    const int b   = bid >> 4;
    const int dc  = (bid >> 2) & 3;
    const int ts  = bid & 3;

    float4 acc[4];
    #pragma unroll
    for (int j = 0; j < 4; ++j) acc[j] = make_float4(0.f, 0.f, 0.f, 0.f);

    #pragma unroll 1
    for (int sc = 0; sc < 8; ++sc) {
        const int tbase = ts * 200 + sc * 25;
        __syncthreads();
        #pragma unroll
        for (int jj = 0; jj < 2; ++jj) {
            const int idx = tid + jj * 256;
            if (idx < 400) {
                const int row = idx >> 4, f4i = idx & 15;
                *(float4*)&xs[row][f4i * 4] =
                    *(const float4*)(x + (size_t)(b * T_ + tbase + row) * D_ + dc * 64 + f4i * 4);
                *(float4*)&rs[row][f4i * 4] =
                    *(const float4*)(r2 + (size_t)(b * T_ + tbase + row) * K_ + f4i * 4);
            }
        }
        __syncthreads();
        #pragma unroll 5
        for (int tt = 0; tt < 25; ++tt) {
            const float4 rv = *(const float4*)&rs[tt][kx * 4];
            const float4 xv = *(const float4*)&xs[tt][dy * 4];
            acc[0].x = fmaf(rv.x, xv.x, acc[0].x); acc[0].y = fmaf(rv.x, xv.y, acc[0].y);
            acc[0].z = fmaf(rv.x, xv.z, acc[0].z); acc[0].w = fmaf(rv.x, xv.w, acc[0].w);
            acc[1].x = fmaf(rv.y, xv.x, acc[1].x); acc[1].y = fmaf(rv.y, xv.y, acc[1].y);
            acc[1].z = fmaf(rv.y, xv.z, acc[1].z); acc[1].w = fmaf(rv.y, xv.w, acc[1].w);
            acc[2].x = fmaf(rv.z, xv.x, acc[2].x); acc[2].y = fmaf(rv.z, xv.y, acc[2].y);
            acc[2].z = fmaf(rv.z, xv.z, acc[2].z); acc[2].w = fmaf(rv.z, xv.w, acc[2].w);
            acc[3].x = fmaf(rv.w, xv.x, acc[3].x); acc[3].y = fmaf(rv.w, xv.y, acc[3].y);
            acc[3].z = fmaf(rv.w, xv.z, acc[3].z); acc[3].w = fmaf(rv.w, xv.w, acc[3].w);
        }
    }

    #pragma unroll
    for (int j = 0; j < 4; ++j) {
        const int k = kx + 16 * j;
        *(float4*)(Pp + (((size_t)ts * B_ + b) * K_ + k) * D_ + dc * 64 + dy * 4) = acc[j];
    }
}

// ---------------- Kernel C: out = (sum_ts Pp)*inv - (S*inv)*mu ----------------
// grid = B*K = 1024 blocks, 64 thr; lane = d-float4
__global__ __launch_bounds__(64) void kernelC(
    const float* __restrict__ Pp, const float* __restrict__ Spart,
    const float* __restrict__ mu, float* __restrict__ out)
{
    const int bk   = blockIdx.x;
    const int b    = bk >> 6, k = bk & 63;
    const int lane = threadIdx.x;

    float s = 0.f;
    #pragma unroll
    for (int p = 0; p < NTILE; ++p)
        s += Spart[((size_t)b * NTILE + p) * K_ + k];

    float4 acc = make_float4(0.f, 0.f, 0.f, 0.f);
    #pragma unroll
    for (int ts = 0; ts < TSPLIT; ++ts) {
        float4 v = ((const float4*)(Pp + (((size_t)ts * B_ + b) * K_ + k) * D_))[lane];
        acc.x += v.x; acc.y += v.y; acc.z += v.z; acc.w += v.w;
    }
    const float inv = 1.f / (s + 1e-9f);
    const float sm  = s * inv;
    float4 m = ((const float4*)(mu + (size_t)k * D_))[lane];
    float4 o;
    o.x = acc.x * inv - sm * m.x;
    o.y = acc.y * inv - sm * m.y;
    o.z = acc.z * inv - sm * m.z;
    o.w = acc.w * inv - sm * m.w;
    ((float4*)out)[(size_t)bk * 64 + lane] = o;
}

extern "C" void kernel_launch(void* const* d_in, const int* in_sizes, int n_in,
                              void* d_out, int out_size, void* d_ws, size_t ws_size,
                              hipStream_t stream) {
    const float* x    = (const float*)d_in[0];
    const float* mu   = (const float*)d_in[1];
    const float* prec = (const float*)d_in[2];
    float* out = (float*)d_out;

    float* r2    = (float*)d_ws;                              // B*T*K      = 819200 f
    float* Pp    = r2 + (size_t)B_ * T_ * K_;                 // 4*B*K*D    = 1048576 f
    float* Spart = Pp + (size_t)TSPLIT * B_ * K_ * D_;        // B*13*K     = 13312 f

    kernelA<<<B_ * NTILE, 256, 0, stream>>>(x, mu, prec, r2, Spart);
    kernelB<<<B_ * 4 * TSPLIT, 256, 0, stream>>>(x, r2, Pp);
    kernelC<<<B_ * K_, 64, 0, stream>>>(Pp, Spart, mu, out);
}

// Round 5
// 88.928 us; speedup vs baseline: 1.5821x; 1.1003x over previous
//
#include <hip/hip_runtime.h>

#define B_ 16
#define T_ 800
#define D_ 256
#define K_ 64
#define NTILE 13     // ceil(800/64) t-tiles for kernel A
#define TSPLIT 8     // kernel B t-split (100 t each)

// ---------------- Kernel A: llk -> softmax over K -> r (k-swizzled), Spart ----------------
// grid = 16*13 = 208 blocks x 512 thr (8 waves -> 2/SIMD). Tile: 64 t x 64 k x 256 d,
// FULL tile staged once (130 KB LDS), single barrier, one long FMA loop.
// thread = (tx=tid>>4 in 0..31, ky=tid&15): owns t = t0+tx*2+i (i<2), k = ky+16j (j<4).
__global__ __launch_bounds__(512, 1) void kernelA(
    const float* __restrict__ x, const float* __restrict__ mu,
    const float* __restrict__ prec, float* __restrict__ r2, float* __restrict__ Spart)
{
    __shared__ float xs[64 * 260];   // [t][d] padded 260 (65 f4) -> conflict-free
    __shared__ float mus[64 * 260];  // [k][d]
    __shared__ float xxs[64];
    __shared__ float mms[64];
    __shared__ float sred[8][64];

    const int tid  = threadIdx.x;
    const int tx   = tid >> 4;     // 0..31
    const int ky   = tid & 15;
    const int b    = blockIdx.x / NTILE;
    const int tile = blockIdx.x % NTILE;
    const int t0   = tile * 64;

    // ---- stage full x tile + full mu (each thread: 8 f4 from each) ----
    #pragma unroll
    for (int jj = 0; jj < 8; ++jj) {
        const int g   = tid + jj * 512;      // 0..4095 f4
        const int row = g >> 6, col = g & 63;
        int trow = t0 + row; if (trow > T_ - 1) trow = T_ - 1;
        *(float4*)&xs[row * 260 + col * 4] =
            *(const float4*)(x + ((size_t)(b * T_ + trow)) * D_ + col * 4);
        *(float4*)&mus[row * 260 + col * 4] =
            *(const float4*)(mu + (size_t)row * D_ + col * 4);
    }
    __syncthreads();

    // ---- xx[t], mm[k]: 8 threads per row, each 8 f4 ----
    {
        const int srow = tid >> 3, sq = tid & 7;
        float xxp = 0.f, mmp = 0.f;
        #pragma unroll
        for (int m = 0; m < 8; ++m) {
            float4 v = *(const float4*)&xs[srow * 260 + (sq * 8 + m) * 4];
            xxp = fmaf(v.x, v.x, xxp); xxp = fmaf(v.y, v.y, xxp);
            xxp = fmaf(v.z, v.z, xxp); xxp = fmaf(v.w, v.w, xxp);
            float4 u = *(const float4*)&mus[srow * 260 + (sq * 8 + m) * 4];
            mmp = fmaf(u.x, u.x, mmp); mmp = fmaf(u.y, u.y, mmp);
            mmp = fmaf(u.z, u.z, mmp); mmp = fmaf(u.w, u.w, mmp);
        }
        xxp += __shfl_xor(xxp, 1); xxp += __shfl_xor(xxp, 2); xxp += __shfl_xor(xxp, 4);
        mmp += __shfl_xor(mmp, 1); mmp += __shfl_xor(mmp, 2); mmp += __shfl_xor(mmp, 4);
        if (sq == 0) { xxs[srow] = xxp; mms[srow] = mmp; }
    }
    __syncthreads();

    // ---- main: 64 dg steps, no barriers. Per step: 2 xv + 4 mv b128 (broadcast), 32 FMA ----
    float acc[2][4];
    #pragma unroll
    for (int i = 0; i < 2; ++i)
        #pragma unroll
        for (int j = 0; j < 4; ++j) acc[i][j] = 0.f;

    #pragma unroll 4
    for (int dg = 0; dg < 64; ++dg) {
        float4 xv[2], mv[4];
        #pragma unroll
        for (int i = 0; i < 2; ++i) xv[i] = *(const float4*)&xs[(tx * 2 + i) * 260 + dg * 4];
        #pragma unroll
        for (int j = 0; j < 4; ++j) mv[j] = *(const float4*)&mus[(ky + 16 * j) * 260 + dg * 4];
        #pragma unroll
        for (int i = 0; i < 2; ++i)
            #pragma unroll
            for (int j = 0; j < 4; ++j) {
                float a = acc[i][j];
                a = fmaf(xv[i].x, mv[j].x, a);
                a = fmaf(xv[i].y, mv[j].y, a);
                a = fmaf(xv[i].z, mv[j].z, a);
                a = fmaf(xv[i].w, mv[j].w, a);
                acc[i][j] = a;
            }
    }

    // ---- softmax over k (16 lanes of same tx hold all 64 k) ----
    float p2[4], mmk[4];
    #pragma unroll
    for (int j = 0; j < 4; ++j) {
        float p = prec[ky + 16 * j];
        p2[j] = p * p;
        mmk[j] = mms[ky + 16 * j];
    }

    float sacc[4] = {0.f, 0.f, 0.f, 0.f};
    #pragma unroll
    for (int i = 0; i < 2; ++i) {
        const int tl = tx * 2 + i;
        const bool valid = (t0 + tl) < T_;
        const float xxv = xxs[tl];
        float llk[4];
        #pragma unroll
        for (int j = 0; j < 4; ++j)
            llk[j] = p2[j] * (2.f * acc[i][j] - xxv - mmk[j]);
        float mx = fmaxf(fmaxf(llk[0], llk[1]), fmaxf(llk[2], llk[3]));
        mx = fmaxf(mx, __shfl_xor(mx, 1)); mx = fmaxf(mx, __shfl_xor(mx, 2));
        mx = fmaxf(mx, __shfl_xor(mx, 4)); mx = fmaxf(mx, __shfl_xor(mx, 8));
        float e[4], ps = 0.f;
        #pragma unroll
        for (int j = 0; j < 4; ++j) { e[j] = __expf(llk[j] - mx); ps += e[j]; }
        ps += __shfl_xor(ps, 1); ps += __shfl_xor(ps, 2);
        ps += __shfl_xor(ps, 4); ps += __shfl_xor(ps, 8);
        const float inv = 1.f / ps;
        float4 rv;
        rv.x = e[0] * inv; rv.y = e[1] * inv; rv.z = e[2] * inv; rv.w = e[3] * inv;
        if (valid) {
            // k-swizzled: f4 slot ky holds k = ky+16j in component j (matches kernelB)
            *(float4*)(r2 + (size_t)(b * T_ + t0 + tl) * K_ + ky * 4) = rv;
            sacc[0] += rv.x; sacc[1] += rv.y; sacc[2] += rv.z; sacc[3] += rv.w;
        }
    }

    // ---- S partials: reduce tx within wave, then across 8 waves via LDS ----
    #pragma unroll
    for (int j = 0; j < 4; ++j) {
        sacc[j] += __shfl_xor(sacc[j], 16);
        sacc[j] += __shfl_xor(sacc[j], 32);
    }
    const int w = tid >> 6;
    if ((tid & 48) == 0) {
        #pragma unroll
        for (int j = 0; j < 4; ++j) sred[w][ky * 4 + j] = sacc[j];
    }
    __syncthreads();
    if (tid < 64) {
        const int k = tid;
        const int slot = (k & 15) * 4 + (k >> 4);
        float s = 0.f;
        #pragma unroll
        for (int q = 0; q < 8; ++q) s += sred[q][slot];
        Spart[((size_t)b * NTILE + tile) * K_ + k] = s;
    }
}

// ---------------- Kernel B: Pp[ts][b][k][d] = sum_{t in 100-chunk} r[t,k] * x[t,d] --------
// grid = 16b * 4dc * 8ts = 512 blocks (2/CU -> 2 waves/SIMD), 256 thr, 50-t staging chunks.
// thread = (kx=tid>>4, dy=tid&15): k = kx+16j (A's swizzle), d = dc*64 + dy*4.
__global__ __launch_bounds__(256, 2) void kernelB(
    const float* __restrict__ x, const float* __restrict__ r2, float* __restrict__ Pp)
{
    __shared__ float xs[50 * 68];
    __shared__ float rs[50 * 68];

    const int tid = threadIdx.x;
    const int kx  = tid >> 4;
    const int dy  = tid & 15;
    const int bid = blockIdx.x;
    const int b   = bid >> 5;
    const int dc  = (bid >> 3) & 3;
    const int ts  = bid & 7;

    float4 acc[4];
    #pragma unroll
    for (int j = 0; j < 4; ++j) acc[j] = make_float4(0.f, 0.f, 0.f, 0.f);

    #pragma unroll 1
    for (int sc = 0; sc < 2; ++sc) {
        const int tbase = ts * 100 + sc * 50;
        __syncthreads();
        #pragma unroll
        for (int jj = 0; jj < 4; ++jj) {
            const int idx = tid + jj * 256;          // 0..1023, need 800
            if (idx < 800) {
                const int row = idx >> 4, f4i = idx & 15;
                *(float4*)&xs[row * 68 + f4i * 4] =
                    *(const float4*)(x + (size_t)(b * T_ + tbase + row) * D_ + dc * 64 + f4i * 4);
                *(float4*)&rs[row * 68 + f4i * 4] =
                    *(const float4*)(r2 + (size_t)(b * T_ + tbase + row) * K_ + f4i * 4);
            }
        }
        __syncthreads();
        #pragma unroll 5
        for (int tt = 0; tt < 50; ++tt) {
            const float4 rv = *(const float4*)&rs[tt * 68 + kx * 4];
            const float4 xv = *(const float4*)&xs[tt * 68 + dy * 4];
            acc[0].x = fmaf(rv.x, xv.x, acc[0].x); acc[0].y = fmaf(rv.x, xv.y, acc[0].y);
            acc[0].z = fmaf(rv.x, xv.z, acc[0].z); acc[0].w = fmaf(rv.x, xv.w, acc[0].w);
            acc[1].x = fmaf(rv.y, xv.x, acc[1].x); acc[1].y = fmaf(rv.y, xv.y, acc[1].y);
            acc[1].z = fmaf(rv.y, xv.z, acc[1].z); acc[1].w = fmaf(rv.y, xv.w, acc[1].w);
            acc[2].x = fmaf(rv.z, xv.x, acc[2].x); acc[2].y = fmaf(rv.z, xv.y, acc[2].y);
            acc[2].z = fmaf(rv.z, xv.z, acc[2].z); acc[2].w = fmaf(rv.z, xv.w, acc[2].w);
            acc[3].x = fmaf(rv.w, xv.x, acc[3].x); acc[3].y = fmaf(rv.w, xv.y, acc[3].y);
            acc[3].z = fmaf(rv.w, xv.z, acc[3].z); acc[3].w = fmaf(rv.w, xv.w, acc[3].w);
        }
    }

    #pragma unroll
    for (int j = 0; j < 4; ++j) {
        const int k = kx + 16 * j;
        *(float4*)(Pp + (((size_t)ts * B_ + b) * K_ + k) * D_ + dc * 64 + dy * 4) = acc[j];
    }
}

// ---------------- Kernel C: out = (sum_ts Pp)*inv - (S*inv)*mu ----------------
// grid = 256 blocks x 256 thr; one f4 of out per thread
__global__ __launch_bounds__(256) void kernelC(
    const float* __restrict__ Pp, const float* __restrict__ Spart,
    const float* __restrict__ mu, float* __restrict__ out)
{
    const int o4 = blockIdx.x * 256 + threadIdx.x;   // 0..65535
    const int d4 = o4 & 63;
    const int k  = (o4 >> 6) & 63;
    const int b  = o4 >> 12;

    float s = 0.f;
    #pragma unroll
    for (int p = 0; p < NTILE; ++p)
        s += Spart[((size_t)b * NTILE + p) * K_ + k];

    float4 acc = make_float4(0.f, 0.f, 0.f, 0.f);
    #pragma unroll
    for (int ts = 0; ts < TSPLIT; ++ts) {
        float4 v = ((const float4*)Pp)[(((size_t)ts * B_ + b) * K_ + k) * 64 + d4];
        acc.x += v.x; acc.y += v.y; acc.z += v.z; acc.w += v.w;
    }
    const float inv = 1.f / (s + 1e-9f);
    const float sm  = s * inv;
    float4 m = ((const float4*)mu)[k * 64 + d4];
    float4 o;
    o.x = acc.x * inv - sm * m.x;
    o.y = acc.y * inv - sm * m.y;
    o.z = acc.z * inv - sm * m.z;
    o.w = acc.w * inv - sm * m.w;
    ((float4*)out)[o4] = o;
}

extern "C" void kernel_launch(void* const* d_in, const int* in_sizes, int n_in,
                              void* d_out, int out_size, void* d_ws, size_t ws_size,
                              hipStream_t stream) {
    const float* x    = (const float*)d_in[0];
    const float* mu   = (const float*)d_in[1];
    const float* prec = (const float*)d_in[2];
    float* out = (float*)d_out;

    float* r2    = (float*)d_ws;                              // B*T*K         = 819200 f
    float* Pp    = r2 + (size_t)B_ * T_ * K_;                 // TSPLIT*B*K*D  = 2097152 f
    float* Spart = Pp + (size_t)TSPLIT * B_ * K_ * D_;        // B*NTILE*K     = 13312 f

    kernelA<<<B_ * NTILE, 512, 0, stream>>>(x, mu, prec, r2, Spart);
    kernelB<<<B_ * 4 * TSPLIT, 256, 0, stream>>>(x, r2, Pp);
    kernelC<<<256, 256, 0, stream>>>(Pp, Spart, mu, out);
}